// Round 6
// baseline (512.235 us; speedup 1.0000x reference)
//
#include <hip/hip_runtime.h>
#include <cstdint>

// Problem constants (fixed by the reference).
#define B_   16
#define C_   306
#define T_   4096
#define M_   270
#define G_   64     // 8x8 grid, strides {8,1}
#define MT_  17     // m-tiles of 16 (M padded to 272)
#define TT   64     // t per block
#define GVP  66     // padded LDS row stride (floats)
#define BDIM 256
#define NW   4

typedef __attribute__((ext_vector_type(8))) short s8;   // 8 bf16 (4 VGPRs) MFMA frag
typedef __attribute__((ext_vector_type(4))) float f4;   // 4 fp32 accumulator
typedef __attribute__((ext_vector_type(4))) int   i4;

// fp32 -> bf16 (RNE) as raw bits; and back.
__device__ __forceinline__ short f2bf(float f) {
    unsigned u = __builtin_bit_cast(unsigned, f);
    u += 0x7FFFu + ((u >> 16) & 1u);
    return (short)(u >> 16);
}
__device__ __forceinline__ float bf2f(short h) {
    return __builtin_bit_cast(float, ((unsigned)(unsigned short)h) << 16);
}

// Hardware LDS fp32 atomic add, fire-and-forget (no return, no wave stall).
// atomicAdd on __shared__ float lowers to a CAS retry loop (denormal safety)
// -- measured ~280us of stall in R1/R3. ds_add_f32 bypasses that.
// !!! The compiler's waitcnt pass cannot see ds ops inside inline asm: R5's
// race (absmax 6.8) came from __syncthreads() lowering to a bare s_barrier.
// Callers MUST drain with lds_fadd_drain() before any barrier/read of gv.
__device__ __forceinline__ void lds_fadd(float* p, float v) {
    __attribute__((address_space(3))) float* lp =
        (__attribute__((address_space(3))) float*)p;
    asm volatile("ds_add_f32 %0, %1" :: "v"(lp), "v"(v) : "memory");
}
__device__ __forceinline__ void lds_fadd_drain() {
    asm volatile("s_waitcnt lgkmcnt(0)" ::: "memory");
}

// ---------------------------------------------------------------------------
// Setup (one kernel): (a) per (b,c) packed corner indices + bilinear weights,
// (b) grid_weights -> MFMA A-operand hi/lo bf16 fragments.
// A[m=lane&15][k=(lane>>4)*8+j] per 16B record -> coalesced dwordx4 load.
// Corner order matches itertools.product((0,1),repeat=2), strides {8,1}.
// ---------------------------------------------------------------------------
__global__ void setup_kernel(const float* __restrict__ pos,
                             const float* __restrict__ gw,
                             uint32_t* __restrict__ cidx,
                             float4* __restrict__ cw,
                             short* __restrict__ whi,
                             short* __restrict__ wlo) {
    int i = blockIdx.x * blockDim.x + threadIdx.x;
    if (i < B_ * C_) {
        float gp0 = (pos[i * 2 + 0] + 1.0f) * 4.0f;   // (p+1)*grid_size/2
        float gp1 = (pos[i * 2 + 1] + 1.0f) * 4.0f;
        float f0 = floorf(gp0), f1 = floorf(gp1);
        int l0 = (int)f0, l1 = (int)f1;
        int h0 = (int)ceilf(gp0), h1 = (int)ceilf(gp1);
        float wh0 = gp0 - f0, wh1 = gp1 - f1;
        float wl0 = 1.0f - wh0, wl1 = 1.0f - wh1;
        uint32_t i00 = (uint32_t)(l0 * 8 + l1);
        uint32_t i01 = (uint32_t)(l0 * 8 + h1);
        uint32_t i10 = (uint32_t)(h0 * 8 + l1);
        uint32_t i11 = (uint32_t)(h0 * 8 + h1);
        cidx[i] = i00 | (i01 << 8) | (i10 << 16) | (i11 << 24);
        cw[i] = make_float4(wl0 * wl1, wl0 * wh1, wh0 * wl1, wh0 * wh1);
    }
    if (i < MT_ * 2 * 64) {
        int lane = i & 63;
        int mt   = i >> 7;
        int ks   = (i >> 6) & 1;
        int m    = mt * 16 + (lane & 15);
        int kb   = ks * 32 + (lane >> 4) * 8;
        #pragma unroll
        for (int j = 0; j < 8; ++j) {
            float w = (m < M_) ? gw[m * G_ + kb + j] : 0.0f;
            short h = f2bf(w);
            whi[i * 8 + j] = h;
            wlo[i * 8 + j] = f2bf(w - bf2f(h));
        }
    }
}

// ---------------------------------------------------------------------------
// Fused kernel, one block per (b, 64-wide t tile):
//  Phase 1 (scatter, HW atomics): waves split c. x-load depends only on c ->
//    fully independent streaming (unroll 8 = 8 loads in flight per wave);
//    corner data uniform; 4x ds_add_f32 fire-and-forget per c.
//    Each x element read exactly once. Explicit lgkm drain before barrier.
//  Phase 2: out[m,t] = W[m,g]*gv[g,t] via bf16x3 MFMA (verified R3/R4,
//    absmax 0.25): W=Wh+Wl, gv=Gh+Gl, keep hh+hl+lh terms.
// ---------------------------------------------------------------------------
__global__ __launch_bounds__(BDIM) void fused_kernel(
    const float* __restrict__ x, const uint32_t* __restrict__ cidx,
    const float4* __restrict__ cw, const i4* __restrict__ whi,
    const i4* __restrict__ wlo, float* __restrict__ out) {
    __shared__ float gv[G_ * GVP];   // 16.9 KB

    const int b    = blockIdx.y;
    const int t0   = blockIdx.x * TT;
    const int tid  = threadIdx.x;
    const int lane = tid & 63;
    const int wave = __builtin_amdgcn_readfirstlane(tid >> 6);
    const int bC   = b * C_;

    for (int i = tid; i < G_ * GVP; i += BDIM) gv[i] = 0.0f;
    __syncthreads();

    // ---- Phase 1: streaming scatter ----
    const float* xp = x + (size_t)bC * T_ + t0 + lane;
    #pragma unroll 8
    for (int c = wave; c < C_; c += NW) {
        uint32_t pk = cidx[bC + c];            // uniform
        float4   w  = cw[bC + c];              // uniform
        float val = xp[(size_t)c * T_];        // coalesced 256B, independent
        lds_fadd(&gv[((pk      ) & 63) * GVP + lane], w.x * val);
        lds_fadd(&gv[((pk >>  8) & 63) * GVP + lane], w.y * val);
        lds_fadd(&gv[((pk >> 16) & 63) * GVP + lane], w.z * val);
        lds_fadd(&gv[((pk >> 24) & 63) * GVP + lane], w.w * val);
    }
    lds_fadd_drain();   // compiler can't see asm ds ops -> drain by hand (R5 race)
    __syncthreads();

    // ---- Phase 2 (unchanged, verified) ----
    const int quad = lane >> 4;
    const int lcol = lane & 15;

    s8 Bh[4][2], Bl[4][2];
    #pragma unroll
    for (int nt = 0; nt < 4; ++nt) {
        #pragma unroll
        for (int ks = 0; ks < 2; ++ks) {
            const int kb = ks * 32 + quad * 8;
            const float* gp = gv + kb * GVP + nt * 16 + lcol;
            #pragma unroll
            for (int j = 0; j < 8; ++j) {
                float v = gp[j * GVP];
                short h = f2bf(v);
                Bh[nt][ks][j] = h;
                Bl[nt][ks][j] = f2bf(v - bf2f(h));
            }
        }
    }

    float* op = out + (size_t)b * M_ * T_ + t0;
    for (int mt = wave; mt < MT_; mt += NW) {
        s8 Ah0 = __builtin_bit_cast(s8, whi[(mt * 2 + 0) * 64 + lane]);
        s8 Ah1 = __builtin_bit_cast(s8, whi[(mt * 2 + 1) * 64 + lane]);
        s8 Al0 = __builtin_bit_cast(s8, wlo[(mt * 2 + 0) * 64 + lane]);
        s8 Al1 = __builtin_bit_cast(s8, wlo[(mt * 2 + 1) * 64 + lane]);
        const int mrow = mt * 16 + quad * 4;
        #pragma unroll
        for (int nt = 0; nt < 4; ++nt) {
            f4 acc = {0.f, 0.f, 0.f, 0.f};
            acc = __builtin_amdgcn_mfma_f32_16x16x32_bf16(Al0, Bh[nt][0], acc, 0, 0, 0);
            acc = __builtin_amdgcn_mfma_f32_16x16x32_bf16(Ah0, Bl[nt][0], acc, 0, 0, 0);
            acc = __builtin_amdgcn_mfma_f32_16x16x32_bf16(Ah0, Bh[nt][0], acc, 0, 0, 0);
            acc = __builtin_amdgcn_mfma_f32_16x16x32_bf16(Al1, Bh[nt][1], acc, 0, 0, 0);
            acc = __builtin_amdgcn_mfma_f32_16x16x32_bf16(Ah1, Bl[nt][1], acc, 0, 0, 0);
            acc = __builtin_amdgcn_mfma_f32_16x16x32_bf16(Ah1, Bh[nt][1], acc, 0, 0, 0);
            #pragma unroll
            for (int r = 0; r < 4; ++r) {
                int m = mrow + r;
                if (m < M_)                     // rows 270/271 are pad
                    op[(size_t)m * T_ + nt * 16 + lcol] = acc[r];
            }
        }
    }
}

extern "C" void kernel_launch(void* const* d_in, const int* in_sizes, int n_in,
                              void* d_out, int out_size, void* d_ws, size_t ws_size,
                              hipStream_t stream) {
    const float* x   = (const float*)d_in[0];
    const float* pos = (const float*)d_in[1];
    const float* gw  = (const float*)d_in[2];
    float* out = (float*)d_out;

    // workspace: cw 78336B | cidx 19584B | whi 34816B | wlo 34816B = 167552B
    float4*   cw   = (float4*)d_ws;
    uint32_t* cidx = (uint32_t*)((char*)d_ws + 78336);
    short*    whi  = (short*)((char*)d_ws + 97920);
    short*    wlo  = (short*)((char*)d_ws + 132736);

    setup_kernel<<<(B_ * C_ + 255) / 256, 256, 0, stream>>>(pos, gw, cidx, cw, whi, wlo);

    dim3 grid(T_ / TT, B_);
    fused_kernel<<<grid, BDIM, 0, stream>>>(x, cidx, cw, (const i4*)whi, (const i4*)wlo, out);
}